// Round 10
// baseline (242.147 us; speedup 1.0000x reference)
//
#include <hip/hip_runtime.h>
#include <hip/hip_bf16.h>

// B=8, T=4096, C=1024, HS=64. Single attention head, causal, scale = C^-0.5.
// Pipeline: wprep (W -> Wt bf16 [192][1024]; zero merge flags) ;
//           proj (q,k bf16, vT bf16; counted-vmcnt pipeline) ;
//           flash (split-KV causal online-softmax, swapped-operand MFMA,
//                  fused last-arriver merge -> final fp32 out).
// Q is pre-scaled by log2(e)/32 in proj, so QK^T is directly log2-domain.

typedef __attribute__((ext_vector_type(8))) short short8;
typedef __attribute__((ext_vector_type(4))) float f32x4;

#define NB 8
#define NT 4096
#define NC 1024
#define NH 64

__device__ __forceinline__ unsigned short f2bf(float f) {
    unsigned int u = __builtin_bit_cast(unsigned int, f);
    u += 0x7fffu + ((u >> 16) & 1u);   // RNE
    return (unsigned short)(u >> 16);
}

__device__ __forceinline__ unsigned cvt_pk_bf16(float lo, float hi) {
    unsigned r;
    asm("v_cvt_pk_bf16_f32 %0, %1, %2" : "=v"(r) : "v"(lo), "v"(hi));
    return r;
}

// async global->LDS, 16B per lane; LDS dest = wave-uniform base + lane*16
#define GLOAD16(gp, lp)                                                        \
    __builtin_amdgcn_global_load_lds(                                          \
        (const __attribute__((address_space(1))) void*)(gp),                   \
        (__attribute__((address_space(3))) void*)(lp), 16, 0, 0)

// ---------------- W prep: Wt[n][c] = W_{n/64}[c][n%64] as bf16 -----------------
// Also zeroes the 512 merge flags (harness doesn't re-poison ws between replays).
__global__ __launch_bounds__(256) void wprep_kernel(
    const float* __restrict__ Wk, const float* __restrict__ Wq,
    const float* __restrict__ Wv, unsigned short* __restrict__ Wt,
    int* __restrict__ flags)
{
    int n = blockIdx.x;            // 0..191
    if (n < 2) flags[n * 256 + threadIdx.x] = 0;
    int which = n >> 6, h = n & 63;
    const float* W = (which == 0) ? Wk : (which == 1) ? Wq : Wv;
    for (int c = threadIdx.x; c < NC; c += 256)
        Wt[(size_t)n * NC + c] = f2bf(W[(size_t)c * NH + h]);
}

// ---------------- Projection GEMM: [32768 x 1024] @ [1024 x 192] ---------------
// Counted-vmcnt pipeline (T4-lite): BK=32, 4 LDS buffers (20 KB each, 80 KB),
// depth-2 prefetch. Per iter: issue stage(k+2) -> s_waitcnt vmcnt(10) (chunk k
// landed; k+1/k+2 stay in flight) -> raw s_barrier -> compute(k).
__global__ __launch_bounds__(256, 2) void proj_kernel(
    const float* __restrict__ x, const unsigned short* __restrict__ Wt,
    unsigned short* __restrict__ qws, unsigned short* __restrict__ kws,
    unsigned short* __restrict__ vtws)
{
    __shared__ char lds[4][20480];   // [buf]: A at 0 (8 KB), B at 8192 (12 KB)

    const int lane = threadIdx.x & 63;
    const int wave = threadIdx.x >> 6;
    const int l15 = lane & 15;
    const int kg = lane >> 4;                  // 0..3
    const int m0 = blockIdx.x * 64;

    const int agS = (lane & 7) ^ (lane >> 3);
    const float* aSrc[2];
#pragma unroll
    for (int j = 0; j < 2; ++j) {
        int i = wave * 2 + j;
        int r = 8 * i + (lane >> 3);
        aSrc[j] = x + (size_t)(m0 + r) * NC + agS * 4;
    }
    const int bgS = (lane & 3) ^ ((lane >> 2) & 3);
    const unsigned short* bSrc[3];
#pragma unroll
    for (int j = 0; j < 3; ++j) {
        int u = wave * 3 + j;
        int r = 16 * u + (lane >> 2);
        bSrc[j] = Wt + (size_t)r * NC + bgS * 8;
    }

    f32x4 acc[12];
#pragma unroll
    for (int i = 0; i < 12; ++i) acc[i] = f32x4{0.f, 0.f, 0.f, 0.f};

#define STAGE_CHUNK(c)                                                         \
    do {                                                                       \
        char* base_ = lds[(c) & 3];                                            \
        _Pragma("unroll")                                                      \
        for (int j = 0; j < 2; ++j)                                            \
            GLOAD16(aSrc[j] + (c) * 32, base_ + (wave * 2 + j) * 1024);        \
        _Pragma("unroll")                                                      \
        for (int j = 0; j < 3; ++j)                                            \
            GLOAD16(bSrc[j] + (c) * 32, base_ + 8192 + (wave * 3 + j) * 1024); \
    } while (0)

    STAGE_CHUNK(0);
    STAGE_CHUNK(1);

    for (int kc = 0; kc < 32; ++kc) {
        if (kc < 30) {
            STAGE_CHUNK(kc + 2);
            asm volatile("s_waitcnt vmcnt(10)" ::: "memory");
        } else if (kc == 30) {
            asm volatile("s_waitcnt vmcnt(5)" ::: "memory");
        } else {
            asm volatile("s_waitcnt vmcnt(0)" ::: "memory");
        }
        __builtin_amdgcn_sched_barrier(0);
        __builtin_amdgcn_s_barrier();

        const char* Ab = lds[kc & 3];
        const char* Bb = lds[kc & 3] + 8192;
        {
            const int r = wave * 16 + l15;
            const int g0 = kg * 2;
            f32x4 a0 = *(const f32x4*)(Ab + r * 128 + ((g0 ^ (r & 7)) * 16));
            f32x4 a1 = *(const f32x4*)(Ab + r * 128 + (((g0 + 1) ^ (r & 7)) * 16));
            short8 a;
            a[0] = (short)f2bf(a0[0]); a[1] = (short)f2bf(a0[1]);
            a[2] = (short)f2bf(a0[2]); a[3] = (short)f2bf(a0[3]);
            a[4] = (short)f2bf(a1[0]); a[5] = (short)f2bf(a1[1]);
            a[6] = (short)f2bf(a1[2]); a[7] = (short)f2bf(a1[3]);
#pragma unroll
            for (int nt = 0; nt < 12; ++nt) {
                int rb = nt * 16 + l15;
                short8 bfrag = *(const short8*)(
                    Bb + rb * 64 + ((kg ^ (rb & 3)) * 16));
                acc[nt] = __builtin_amdgcn_mfma_f32_16x16x32_bf16(a, bfrag, acc[nt], 0, 0, 0);
            }
        }
    }
#undef STAGE_CHUNK

    const float cs = 0.04508422f;   // log2(e) / 32  (folded into q)
    const int crow0 = m0 + wave * 16 + (kg << 2);
#pragma unroll
    for (int nt = 0; nt < 12; ++nt) {
        int n = nt * 16 + l15;
        int which = n >> 6;
        int h = n & 63;
#pragma unroll
        for (int r = 0; r < 4; ++r) {
            int gm = crow0 + r;
            float av = acc[nt][r];
            if (which == 1) av *= cs;
            unsigned short v = f2bf(av);
            if (which == 0) {
                kws[(size_t)gm * NH + h] = v;
            } else if (which == 1) {
                qws[(size_t)gm * NH + h] = v;
            } else {
                int bb = gm >> 12, tt = gm & 4095;
                vtws[((size_t)(bb * NH + h)) * NT + tt] = v;
            }
        }
    }
}

// ---------------- Flash attention (causal, swapped operands, split-KV) ---------
// 1024 blocks = 2 KV-halves x (8 batches x 64 q-tiles). 4 waves x 16 q-rows.
// Fused combine: each block writes its fp32 partial, threadfence, atomicAdd on
// the per-(b,qt) flag; the SECOND arriver reads the partner's partial, merges
// with its register-resident O/m/l, writes final out. Merge math is symmetric
// -> bit-identical output regardless of arrival order (deterministic).
__global__ __launch_bounds__(256) void flash_kernel(
    const unsigned short* __restrict__ qws, const unsigned short* __restrict__ kws,
    const unsigned short* __restrict__ vtws,
    float* __restrict__ opart, float* __restrict__ mlpart,
    int* __restrict__ flags, float* __restrict__ out)
{
    __shared__ unsigned short Kbuf[2][64 * 64];
    __shared__ unsigned short Vbuf[2][64 * 64];
    __shared__ unsigned short Plds[4 * 16 * 64];   // per-wave 16x64 P strips
    __shared__ int role;

    const int id = blockIdx.x;
    const int kvh = id >> 9;           // KV half: 0 = [0,h), 1 = [h,nkv)
    const int rem9 = id & 511;
    const int lighthalf = rem9 >> 8;   // 0: heavy q-tiles, 1: light
    const int rem = rem9 & 255;
    const int b = rem & 7;
    const int i32 = rem >> 3;          // 0..31
    const int qt = lighthalf ? i32 : (63 - i32);
    const int nkv = qt + 1;
    const int hsp = nkv - (nkv >> 1);  // ceil(nkv/2)
    const int k0 = kvh ? hsp : 0;
    const int k1 = kvh ? nkv : hsp;    // k0==k1 possible (qt=0, half B): loop skips
    const int pid_ = (kvh << 9) | ((b << 6) | qt);

    float* mlp = mlpart + (size_t)pid_ * 128;
    float* op  = opart + (size_t)pid_ * 4096;

    const int lane = threadIdx.x & 63;
    const int wave = threadIdx.x >> 6;
    const int l15 = lane & 15;
    const int kg = lane >> 4;

    // ---- staging sources (pre-inverse-swizzled, loop-invariant per lane) ----
    const int sg = (lane & 7) ^ (lane >> 3);   // swizzled source granule
    const unsigned short* kSrc[2];
    const unsigned short* vSrc[2];
#pragma unroll
    for (int j = 0; j < 2; ++j) {
        int r = 16 * wave + 8 * j + (lane >> 3);   // tile-local row 0..63
        kSrc[j] = kws + ((size_t)(b * NT) + r) * NH + sg * 8;
        vSrc[j] = vtws + ((size_t)(b * NH + r)) * NT + sg * 8;
    }

    // Q fragments (pre-scaled by log2(e)/32): lane holds Q[q=l15][d=kg*8+j]
    short8 qf[2];
    {
        const unsigned short* qp =
            qws + ((size_t)(b * NT + qt * 64 + wave * 16 + l15)) * NH + kg * 8;
        qf[0] = *(const short8*)(qp);
        qf[1] = *(const short8*)(qp + 32);
    }

    f32x4 o[4];        // O^T: o[dt][r] = O[q=l15][d = dt*16 + kg*4 + r]
#pragma unroll
    for (int dt = 0; dt < 4; ++dt) o[dt] = f32x4{0.f, 0.f, 0.f, 0.f};
    float m_r = -INFINITY;   // row max (uniform across the row's 4 kg-lanes)
    float l_r = 0.f;         // per-lane PARTIAL sum (own 16 keys)

    char* pw = (char*)Plds + wave * 2048;
    const int pswz = (l15 & 7) << 4;

    // prologue: stage tile min(k0, 63) into buf 0 (harmless if loop is empty)
    const int kst = (k0 < 64) ? k0 : 63;
#pragma unroll
    for (int j = 0; j < 2; ++j) {
        int i = 2 * wave + j;
        GLOAD16(kSrc[j] + (size_t)kst * 64 * NH, (char*)Kbuf[0] + i * 1024);
        GLOAD16(vSrc[j] + (size_t)kst * 64,      (char*)Vbuf[0] + i * 1024);
    }
    __syncthreads();

    int cur = 0;
    for (int kv = k0; kv < k1; ++kv) {
        // stage next tile into the other buffer (async, fire-and-forget)
        if (kv + 1 < k1) {
#pragma unroll
            for (int j = 0; j < 2; ++j) {
                int i = 2 * wave + j;
                GLOAD16(kSrc[j] + (size_t)(kv + 1) * 64 * NH,
                        (char*)Kbuf[cur ^ 1] + i * 1024);
                GLOAD16(vSrc[j] + (size_t)(kv + 1) * 64,
                        (char*)Vbuf[cur ^ 1] + i * 1024);
            }
        }

        const char* Kb = (const char*)Kbuf[cur];
        const char* Vb = (const char*)Vbuf[cur];

        // S^T = mfma(K, Q): st[jt][r] = S[q=l15][key = jt*16 + kg*4 + r]
        f32x4 st[4];
#pragma unroll
        for (int jt = 0; jt < 4; ++jt) st[jt] = f32x4{0.f, 0.f, 0.f, 0.f};
        __builtin_amdgcn_s_setprio(1);
#pragma unroll
        for (int ks = 0; ks < 2; ++ks) {
            const int cbb = ks * 64 + kg * 16;
#pragma unroll
            for (int jt = 0; jt < 4; ++jt) {
                int krow = jt * 16 + l15;
                short8 kf = *(const short8*)(Kb + krow * 128 +
                                             (cbb ^ ((krow & 7) << 4)));
                st[jt] = __builtin_amdgcn_mfma_f32_16x16x32_bf16(kf, qf[ks], st[jt], 0, 0, 0);
            }
        }
        __builtin_amdgcn_s_setprio(0);

        // causal mask: only the diagonal tile (uniform branch)
        if (kv == qt) {
#pragma unroll
            for (int jt = 0; jt < 4; ++jt)
#pragma unroll
                for (int r = 0; r < 4; ++r)
                    if (jt * 16 + (kg << 2) + r > wave * 16 + l15)
                        st[jt][r] = -1e30f;
        }

        // lane-local max over own 16 keys (no cross-lane)
        float lmax;
        {
            float t0 = fmaxf(fmaxf(st[0][0], st[0][1]), fmaxf(st[0][2], st[0][3]));
            float t1 = fmaxf(fmaxf(st[1][0], st[1][1]), fmaxf(st[1][2], st[1][3]));
            float t2 = fmaxf(fmaxf(st[2][0], st[2][1]), fmaxf(st[2][2], st[2][3]));
            float t3 = fmaxf(fmaxf(st[3][0], st[3][1]), fmaxf(st[3][2], st[3][3]));
            lmax = fmaxf(fmaxf(t0, t1), fmaxf(t2, t3));
        }

        // defer-max: rescale only when some row grew past m+8 (rare)
        if (!__all(lmax <= m_r + 8.0f)) {
            float pmax = lmax;
            pmax = fmaxf(pmax, __shfl_xor(pmax, 16));
            pmax = fmaxf(pmax, __shfl_xor(pmax, 32));
            float mn = fmaxf(m_r, pmax);
            float alpha = __builtin_amdgcn_exp2f(m_r - mn);
            m_r = mn;
            l_r *= alpha;
#pragma unroll
            for (int dt = 0; dt < 4; ++dt)
#pragma unroll
                for (int r = 0; r < 4; ++r)
                    o[dt][r] *= alpha;
        }

        // P = exp2(S - m), bounded by 2^8; accumulate per-lane partial l
#pragma unroll
        for (int jt = 0; jt < 4; ++jt)
#pragma unroll
            for (int r = 0; r < 4; ++r)
                st[jt][r] = __builtin_amdgcn_exp2f(st[jt][r] - m_r);
        {
            float t0 = (st[0][0] + st[0][1]) + (st[0][2] + st[0][3]);
            float t1 = (st[1][0] + st[1][1]) + (st[1][2] + st[1][3]);
            float t2 = (st[2][0] + st[2][1]) + (st[2][2] + st[2][3]);
            float t3 = (st[3][0] + st[3][1]) + (st[3][2] + st[3][3]);
            l_r += (t0 + t1) + (t2 + t3);
        }

        // pack P to bf16, per-wave LDS strip round-trip -> B-frag layout
#pragma unroll
        for (int jt = 0; jt < 4; ++jt) {
            unsigned w0 = cvt_pk_bf16(st[jt][0], st[jt][1]);
            unsigned w1 = cvt_pk_bf16(st[jt][2], st[jt][3]);
            uint2 t; t.x = w0; t.y = w1;
            *(uint2*)(pw + l15 * 128 + ((jt * 32 + kg * 8) ^ pswz)) = t;
        }
        short8 pf[2];
#pragma unroll
        for (int ks = 0; ks < 2; ++ks)
            pf[ks] = *(const short8*)(pw + l15 * 128 + ((ks * 64 + kg * 16) ^ pswz));

        // O^T += mfma(V^T, P^T)
        __builtin_amdgcn_s_setprio(1);
#pragma unroll
        for (int ks = 0; ks < 2; ++ks) {
            const int cbb = ks * 64 + kg * 16;
#pragma unroll
            for (int dt = 0; dt < 4; ++dt) {
                int vrow = dt * 16 + l15;
                short8 vf = *(const short8*)(Vb + vrow * 128 +
                                             (cbb ^ ((vrow & 7) << 4)));
                o[dt] = __builtin_amdgcn_mfma_f32_16x16x32_bf16(vf, pf[ks], o[dt], 0, 0, 0);
            }
        }
        __builtin_amdgcn_s_setprio(0);

        // single barrier: drains staging vmcnt + this iter's LDS reads
        __syncthreads();
        cur ^= 1;
    }

    // epilogue: reduce partial l across the row's 4 kg-lanes; write partial
    float lsum = l_r;
    lsum += __shfl_xor(lsum, 16);
    lsum += __shfl_xor(lsum, 32);
    const int q = wave * 16 + l15;
    float* orow = op + q * 64 + (kg << 2);
#pragma unroll
    for (int dt = 0; dt < 4; ++dt)
        *(f32x4*)(orow + dt * 16) = o[dt];
    if (kg == 0) {
        mlp[q] = m_r;
        mlp[64 + q] = lsum;
    }

    // ---- fused combine: last arriver merges (canonical split-K pattern) ----
    __threadfence();                       // release our partial device-wide
    __syncthreads();                       // all threads' stores fenced
    if (threadIdx.x == 0)
        role = atomicAdd(&flags[(b << 6) | qt], 1);
    __syncthreads();
    if (role == 0) return;                 // first arriver: partial published

    __threadfence();                       // acquire partner's stores
    const int partner = pid_ ^ (1 << 9);   // other KV half
    const float* mlP = mlpart + (size_t)partner * 128;
    const float* opP = opart + (size_t)partner * 4096;
    float mP = mlP[q], lP = mlP[64 + q];
    float ms = fmaxf(m_r, mP);
    float eO = __builtin_amdgcn_exp2f(m_r - ms);
    float eP = __builtin_amdgcn_exp2f(mP - ms);
    float dinv = __builtin_amdgcn_rcpf(eO * lsum + eP * lP);
    const float* prow = opP + q * 64 + (kg << 2);
    float* grow = out + ((size_t)(b * NT) + qt * 64 + q) * NH + (kg << 2);
#pragma unroll
    for (int dt = 0; dt < 4; ++dt) {
        f32x4 pv = *(const f32x4*)(prow + dt * 16);
        f32x4 rr;
        rr[0] = (eO * o[dt][0] + eP * pv[0]) * dinv;
        rr[1] = (eO * o[dt][1] + eP * pv[1]) * dinv;
        rr[2] = (eO * o[dt][2] + eP * pv[2]) * dinv;
        rr[3] = (eO * o[dt][3] + eP * pv[3]) * dinv;
        *(f32x4*)(grow + dt * 16) = rr;
    }
}

extern "C" void kernel_launch(void* const* d_in, const int* in_sizes, int n_in,
                              void* d_out, int out_size, void* d_ws, size_t ws_size,
                              hipStream_t stream) {
    const float* x  = (const float*)d_in[0];
    const float* Wk = (const float*)d_in[1];
    const float* Wq = (const float*)d_in[2];
    const float* Wv = (const float*)d_in[3];
    float* out = (float*)d_out;

    unsigned short* ws   = (unsigned short*)d_ws;
    const size_t qkv_elems = (size_t)NB * NT * NH;   // 2M elements each
    unsigned short* qws  = ws;
    unsigned short* kws  = qws + qkv_elems;
    unsigned short* vtws = kws + qkv_elems;
    unsigned short* Wt   = vtws + qkv_elems;          // 192*1024 bf16
    float* opart  = (float*)(Wt + (size_t)192 * NC);  // 1024 tiles x 4096 f32
    float* mlpart = opart + (size_t)1024 * 4096;      // 1024 x 128 f32
    int*   flags  = (int*)(mlpart + (size_t)1024 * 128);  // 512 ints

    wprep_kernel<<<dim3(192), dim3(256), 0, stream>>>(Wk, Wq, Wv, Wt, flags);
    proj_kernel<<<dim3(512), dim3(256), 0, stream>>>(x, Wt, qws, kws, vtws);
    flash_kernel<<<dim3(1024), dim3(256), 0, stream>>>(qws, kws, vtws, opart, mlpart, flags, out);
}

// Round 11
// 96.440 us; speedup vs baseline: 2.5108x; 2.5108x over previous
//
#include <hip/hip_runtime.h>
#include <hip/hip_bf16.h>

// B=8, T=4096, C=1024, HS=64. Single attention head, causal, scale = C^-0.5.
// Pipeline: wprep (W -> Wt bf16 [192][1024]) ; proj (q,k bf16, vT bf16; counted-vmcnt pipeline) ;
//           flash (split-KV causal online-softmax, swapped-operand MFMA,
//                  32-key tiles, 4-buffer counted-vmcnt pipeline) ;
//           combine (merge the two KV halves, normalize, fp32 out).
// Q is pre-scaled by log2(e)/32 in proj, so QK^T is directly log2-domain.

typedef __attribute__((ext_vector_type(8))) short short8;
typedef __attribute__((ext_vector_type(4))) float f32x4;

#define NB 8
#define NT 4096
#define NC 1024
#define NH 64

__device__ __forceinline__ unsigned short f2bf(float f) {
    unsigned int u = __builtin_bit_cast(unsigned int, f);
    u += 0x7fffu + ((u >> 16) & 1u);   // RNE
    return (unsigned short)(u >> 16);
}

__device__ __forceinline__ unsigned cvt_pk_bf16(float lo, float hi) {
    unsigned r;
    asm("v_cvt_pk_bf16_f32 %0, %1, %2" : "=v"(r) : "v"(lo), "v"(hi));
    return r;
}

// async global->LDS, 16B per lane; LDS dest = wave-uniform base + lane*16
#define GLOAD16(gp, lp)                                                        \
    __builtin_amdgcn_global_load_lds(                                          \
        (const __attribute__((address_space(1))) void*)(gp),                   \
        (__attribute__((address_space(3))) void*)(lp), 16, 0, 0)

// ---------------- W prep: Wt[n][c] = W_{n/64}[c][n%64] as bf16 -----------------
__global__ __launch_bounds__(256) void wprep_kernel(
    const float* __restrict__ Wk, const float* __restrict__ Wq,
    const float* __restrict__ Wv, unsigned short* __restrict__ Wt)
{
    int n = blockIdx.x;            // 0..191
    int which = n >> 6, h = n & 63;
    const float* W = (which == 0) ? Wk : (which == 1) ? Wq : Wv;
    for (int c = threadIdx.x; c < NC; c += 256)
        Wt[(size_t)n * NC + c] = f2bf(W[(size_t)c * NH + h]);
}

// ---------------- Projection GEMM: [32768 x 1024] @ [1024 x 192] ---------------
// Counted-vmcnt pipeline: BK=32, 4 LDS buffers (20 KB each), depth-2 prefetch.
__global__ __launch_bounds__(256, 2) void proj_kernel(
    const float* __restrict__ x, const unsigned short* __restrict__ Wt,
    unsigned short* __restrict__ qws, unsigned short* __restrict__ kws,
    unsigned short* __restrict__ vtws)
{
    __shared__ char lds[4][20480];   // [buf]: A at 0 (8 KB), B at 8192 (12 KB)

    const int lane = threadIdx.x & 63;
    const int wave = threadIdx.x >> 6;
    const int l15 = lane & 15;
    const int kg = lane >> 4;                  // 0..3
    const int m0 = blockIdx.x * 64;

    const int agS = (lane & 7) ^ (lane >> 3);
    const float* aSrc[2];
#pragma unroll
    for (int j = 0; j < 2; ++j) {
        int i = wave * 2 + j;
        int r = 8 * i + (lane >> 3);
        aSrc[j] = x + (size_t)(m0 + r) * NC + agS * 4;
    }
    const int bgS = (lane & 3) ^ ((lane >> 2) & 3);
    const unsigned short* bSrc[3];
#pragma unroll
    for (int j = 0; j < 3; ++j) {
        int u = wave * 3 + j;
        int r = 16 * u + (lane >> 2);
        bSrc[j] = Wt + (size_t)r * NC + bgS * 8;
    }

    f32x4 acc[12];
#pragma unroll
    for (int i = 0; i < 12; ++i) acc[i] = f32x4{0.f, 0.f, 0.f, 0.f};

#define STAGE_CHUNK(c)                                                         \
    do {                                                                       \
        char* base_ = lds[(c) & 3];                                            \
        _Pragma("unroll")                                                      \
        for (int j = 0; j < 2; ++j)                                            \
            GLOAD16(aSrc[j] + (c) * 32, base_ + (wave * 2 + j) * 1024);        \
        _Pragma("unroll")                                                      \
        for (int j = 0; j < 3; ++j)                                            \
            GLOAD16(bSrc[j] + (c) * 32, base_ + 8192 + (wave * 3 + j) * 1024); \
    } while (0)

    STAGE_CHUNK(0);
    STAGE_CHUNK(1);

    for (int kc = 0; kc < 32; ++kc) {
        if (kc < 30) {
            STAGE_CHUNK(kc + 2);
            asm volatile("s_waitcnt vmcnt(10)" ::: "memory");
        } else if (kc == 30) {
            asm volatile("s_waitcnt vmcnt(5)" ::: "memory");
        } else {
            asm volatile("s_waitcnt vmcnt(0)" ::: "memory");
        }
        __builtin_amdgcn_sched_barrier(0);
        __builtin_amdgcn_s_barrier();

        const char* Ab = lds[kc & 3];
        const char* Bb = lds[kc & 3] + 8192;
        {
            const int r = wave * 16 + l15;
            const int g0 = kg * 2;
            f32x4 a0 = *(const f32x4*)(Ab + r * 128 + ((g0 ^ (r & 7)) * 16));
            f32x4 a1 = *(const f32x4*)(Ab + r * 128 + (((g0 + 1) ^ (r & 7)) * 16));
            short8 a;
            a[0] = (short)f2bf(a0[0]); a[1] = (short)f2bf(a0[1]);
            a[2] = (short)f2bf(a0[2]); a[3] = (short)f2bf(a0[3]);
            a[4] = (short)f2bf(a1[0]); a[5] = (short)f2bf(a1[1]);
            a[6] = (short)f2bf(a1[2]); a[7] = (short)f2bf(a1[3]);
#pragma unroll
            for (int nt = 0; nt < 12; ++nt) {
                int rb = nt * 16 + l15;
                short8 bfrag = *(const short8*)(
                    Bb + rb * 64 + ((kg ^ (rb & 3)) * 16));
                acc[nt] = __builtin_amdgcn_mfma_f32_16x16x32_bf16(a, bfrag, acc[nt], 0, 0, 0);
            }
        }
    }
#undef STAGE_CHUNK

    const float cs = 0.04508422f;   // log2(e) / 32  (folded into q)
    const int crow0 = m0 + wave * 16 + (kg << 2);
#pragma unroll
    for (int nt = 0; nt < 12; ++nt) {
        int n = nt * 16 + l15;
        int which = n >> 6;
        int h = n & 63;
#pragma unroll
        for (int r = 0; r < 4; ++r) {
            int gm = crow0 + r;
            float av = acc[nt][r];
            if (which == 1) av *= cs;
            unsigned short v = f2bf(av);
            if (which == 0) {
                kws[(size_t)gm * NH + h] = v;
            } else if (which == 1) {
                qws[(size_t)gm * NH + h] = v;
            } else {
                int bb = gm >> 12, tt = gm & 4095;
                vtws[((size_t)(bb * NH + h)) * NT + tt] = v;
            }
        }
    }
}

// ---------------- Flash attention (causal, swapped operands, split-KV) ---------
// 1024 blocks = 2 KV-halves x (8 b x 64 q-tiles of 64 rows). 4 waves x 16 q-rows.
// 32-key KV tiles, 4 LDS buffers, counted-vmcnt pipeline (stage depth 2):
//   iter kv: issue stage(kv+2) -> vmcnt(4) (own stage(kv) landed; kv+1/kv+2 in
//   flight) -> raw s_barrier (all waves' stage(kv) landed) -> compute(kv).
// Buffer safety: stage(kv+2) writes buf[(kv+2)&3]; its previous reader is
// compute(kv-2), finished by every wave before barrier(kv-1), and the issue is
// after this wave passed barrier(kv-1). Q loads drained (vmcnt(0)) pre-loop so
// manual counts are exact. Split [0..2qt+2) into two equal halves of qt+1 tiles.
__global__ __launch_bounds__(256) void flash_kernel(
    const unsigned short* __restrict__ qws, const unsigned short* __restrict__ kws,
    const unsigned short* __restrict__ vtws,
    float* __restrict__ opart, float* __restrict__ mlpart)
{
    __shared__ unsigned short Kbuf[4][32 * 64];    // 4 x 4 KB  (32 keys x 64 d)
    __shared__ unsigned short Vbuf[4][64 * 32];    // 4 x 4 KB  (64 d x 32 keys)
    __shared__ unsigned short Plds[4][16 * 32];    // per-wave 1 KB strips

    const int id = blockIdx.x;
    const int kvh = id >> 9;           // 0: tiles [0,qt+1), 1: [qt+1, 2qt+2)
    const int rem9 = id & 511;
    const int lighthalf = rem9 >> 8;
    const int rem = rem9 & 255;
    const int b = rem & 7;
    const int i32 = rem >> 3;
    const int qt = lighthalf ? i32 : (63 - i32);   // heavy-first
    const int k0 = kvh ? (qt + 1) : 0;
    const int k1 = kvh ? (2 * qt + 2) : (qt + 1);  // always k1 > k0
    const int pid_ = (kvh << 9) | ((b << 6) | qt);

    float* mlp = mlpart + (size_t)pid_ * 128;
    float* op  = opart + (size_t)pid_ * 4096;

    const int lane = threadIdx.x & 63;
    const int wave = threadIdx.x >> 6;
    const int l15 = lane & 15;
    const int kg = lane >> 4;

    // staging sources (pre-inverse-swizzled, loop-invariant per lane):
    // K tile = 4 instrs (1/wave), instr w covers key-rows 8w..8w+7 (128 B rows)
    const unsigned short* kSrc =
        kws + ((size_t)(b * NT) + 8 * wave + (lane >> 3)) * NH +
        (((lane & 7) ^ (lane >> 3)) * 8);
    // V tile = 4 instrs (1/wave), instr w covers d-rows 16w..16w+15 (64 B rows)
    const unsigned short* vSrc =
        vtws + ((size_t)(b * NH) + 16 * wave + (lane >> 2)) * NT +
        (((lane & 3) ^ ((lane >> 2) & 3)) * 8);

    // Q fragments (pre-scaled): lane holds Q[q=l15][d = ks*32 + kg*8 + j]
    short8 qf[2];
    {
        const unsigned short* qp =
            qws + ((size_t)(b * NT + qt * 64 + wave * 16 + l15)) * NH + kg * 8;
        qf[0] = *(const short8*)(qp);
        qf[1] = *(const short8*)(qp + 32);
    }
    // drain Q loads so manual vmcnt counts below are exact
    asm volatile("s_waitcnt vmcnt(0)" ::: "memory");

    f32x4 o[4];        // O^T: o[dt][r] = O[q=l15][d = dt*16 + kg*4 + r]
#pragma unroll
    for (int dt = 0; dt < 4; ++dt) o[dt] = f32x4{0.f, 0.f, 0.f, 0.f};
    float m_r = -INFINITY;   // running max (valid for both: any m >= rowmax ok)
    float l_r = 0.f;         // per-lane partial sum (own 8 keys per tile)

    char* pw = (char*)Plds[wave];
    const int qbw = qt * 64 + wave * 16;   // wave's minimum q row

#define STAGE_KV(t)                                                            \
    do {                                                                       \
        GLOAD16(kSrc + (size_t)(t) * 32 * NH, (char*)Kbuf[(t) & 3] + wave * 1024); \
        GLOAD16(vSrc + (t) * 32,              (char*)Vbuf[(t) & 3] + wave * 1024); \
    } while (0)

    STAGE_KV(k0);
    if (k0 + 1 < k1) STAGE_KV(k0 + 1);

    for (int kv = k0; kv < k1; ++kv) {
        if (kv + 2 < k1) {
            STAGE_KV(kv + 2);
            asm volatile("s_waitcnt vmcnt(4)" ::: "memory");
        } else if (kv + 1 < k1) {
            asm volatile("s_waitcnt vmcnt(2)" ::: "memory");
        } else {
            asm volatile("s_waitcnt vmcnt(0)" ::: "memory");
        }
        __builtin_amdgcn_sched_barrier(0);
        __builtin_amdgcn_s_barrier();

        const char* Kb = (const char*)Kbuf[kv & 3];
        const char* Vb = (const char*)Vbuf[kv & 3];

        // S^T = mfma(K, Q): st[jt][r] = S[q=l15][key = jt*16 + kg*4 + r]
        f32x4 st[2];
        st[0] = f32x4{0.f, 0.f, 0.f, 0.f};
        st[1] = f32x4{0.f, 0.f, 0.f, 0.f};
        __builtin_amdgcn_s_setprio(1);
#pragma unroll
        for (int ks = 0; ks < 2; ++ks) {
            const int cg = ks * 4 + kg;        // logical 16B granule in K row
#pragma unroll
            for (int jt = 0; jt < 2; ++jt) {
                int krow = jt * 16 + l15;
                short8 kf = *(const short8*)(Kb + krow * 128 +
                                             ((cg ^ (krow & 7)) << 4));
                st[jt] = __builtin_amdgcn_mfma_f32_16x16x32_bf16(kf, qf[ks], st[jt], 0, 0, 0);
            }
        }
        __builtin_amdgcn_s_setprio(0);

        // causal mask (wave-uniform guard; elementwise only near the diagonal)
        if (kv * 32 + 31 > qbw) {
#pragma unroll
            for (int jt = 0; jt < 2; ++jt)
#pragma unroll
                for (int r = 0; r < 4; ++r)
                    if (kv * 32 + jt * 16 + (kg << 2) + r > qbw + l15)
                        st[jt][r] = -1e30f;
        }

        // lane-local max over own 8 keys
        float lmax;
        {
            float t0 = fmaxf(fmaxf(st[0][0], st[0][1]), fmaxf(st[0][2], st[0][3]));
            float t1 = fmaxf(fmaxf(st[1][0], st[1][1]), fmaxf(st[1][2], st[1][3]));
            lmax = fmaxf(t0, t1);
        }

        // defer-max: rescale only when some row grew past m+8 (rare)
        if (!__all(lmax <= m_r + 8.0f)) {
            float pmax = lmax;
            pmax = fmaxf(pmax, __shfl_xor(pmax, 16));
            pmax = fmaxf(pmax, __shfl_xor(pmax, 32));
            float mn = fmaxf(m_r, pmax);
            float alpha = __builtin_amdgcn_exp2f(m_r - mn);
            m_r = mn;
            l_r *= alpha;
#pragma unroll
            for (int dt = 0; dt < 4; ++dt)
#pragma unroll
                for (int r = 0; r < 4; ++r)
                    o[dt][r] *= alpha;
        }

        // P = exp2(S - m); accumulate per-lane partial l
#pragma unroll
        for (int jt = 0; jt < 2; ++jt)
#pragma unroll
            for (int r = 0; r < 4; ++r)
                st[jt][r] = __builtin_amdgcn_exp2f(st[jt][r] - m_r);
        l_r += ((st[0][0] + st[0][1]) + (st[0][2] + st[0][3])) +
               ((st[1][0] + st[1][1]) + (st[1][2] + st[1][3]));

        // pack P -> per-wave LDS strip (64 B rows, granule ^= (l15&3))
#pragma unroll
        for (int jt = 0; jt < 2; ++jt) {
            uint2 t;
            t.x = cvt_pk_bf16(st[jt][0], st[jt][1]);
            t.y = cvt_pk_bf16(st[jt][2], st[jt][3]);
            int phys = (jt * 2 + (kg >> 1)) ^ (l15 & 3);
            *(uint2*)(pw + l15 * 64 + (phys << 4) + ((kg & 1) << 3)) = t;
        }
        // read P^T B-frag: keys kg*8..kg*8+7 of row q=l15
        short8 pf = *(const short8*)(pw + l15 * 64 + (((kg ^ (l15 & 3))) << 4));

        // O^T += mfma(V^T, P^T)  (K=32: single k-step)
        __builtin_amdgcn_s_setprio(1);
#pragma unroll
        for (int dt = 0; dt < 4; ++dt) {
            int vrow = dt * 16 + l15;
            short8 vf = *(const short8*)(Vb + vrow * 64 +
                                         (((kg ^ (vrow & 3))) << 4));
            o[dt] = __builtin_amdgcn_mfma_f32_16x16x32_bf16(vf, pf, o[dt], 0, 0, 0);
        }
        __builtin_amdgcn_s_setprio(0);
        // no trailing barrier: next iteration's counted vmcnt + s_barrier cover
        // both staging completion and buffer-reuse safety (see header comment).
    }
#undef STAGE_KV

    // epilogue: reduce partial l across the row's 4 kg-lanes; store O^T + (m,l)
    float lsum = l_r;
    lsum += __shfl_xor(lsum, 16);
    lsum += __shfl_xor(lsum, 32);
    const int q = wave * 16 + l15;
    float* orow = op + q * 64 + (kg << 2);
#pragma unroll
    for (int dt = 0; dt < 4; ++dt)
        *(f32x4*)(orow + dt * 16) = o[dt];
    if (kg == 0) {
        mlp[q] = m_r;
        mlp[64 + q] = lsum;
    }
}

// ---------------- Combine: merge the two KV halves, normalize -----------------
// 512 blocks = (b, qt). O = (eA*OA + eB*OB) / (eA*lA + eB*lB), e = exp2(m - m*).
__global__ __launch_bounds__(256) void combine_kernel(
    const float* __restrict__ opart, const float* __restrict__ mlpart,
    float* __restrict__ out)
{
    const int cid = blockIdx.x;          // = (b<<6)|qt
    const int b = cid >> 6, qt = cid & 63;
    const float* mlA = mlpart + (size_t)cid * 128;
    const float* mlB = mlpart + (size_t)(512 + cid) * 128;
    const f32x4* oA = (const f32x4*)(opart + (size_t)cid * 4096);
    const f32x4* oB = (const f32x4*)(opart + (size_t)(512 + cid) * 4096);
    f32x4* og = (f32x4*)out;

#pragma unroll
    for (int i = 0; i < 4; ++i) {
        int g = threadIdx.x + i * 256;   // 0..1023 f32x4 groups
        int row = g >> 4;
        float mA = mlA[row], lA = mlA[64 + row];
        float mB = mlB[row], lB = mlB[64 + row];
        float ms = fmaxf(mA, mB);
        float eA = __builtin_amdgcn_exp2f(mA - ms);
        float eB = __builtin_amdgcn_exp2f(mB - ms);
        float dinv = __builtin_amdgcn_rcpf(eA * lA + eB * lB);
        f32x4 a = oA[g], c = oB[g];
        f32x4 r;
        r[0] = (eA * a[0] + eB * c[0]) * dinv;
        r[1] = (eA * a[1] + eB * c[1]) * dinv;
        r[2] = (eA * a[2] + eB * c[2]) * dinv;
        r[3] = (eA * a[3] + eB * c[3]) * dinv;
        og[((size_t)(b * NT) + qt * 64 + row) * 16 + (g & 15)] = r;
    }
}

extern "C" void kernel_launch(void* const* d_in, const int* in_sizes, int n_in,
                              void* d_out, int out_size, void* d_ws, size_t ws_size,
                              hipStream_t stream) {
    const float* x  = (const float*)d_in[0];
    const float* Wk = (const float*)d_in[1];
    const float* Wq = (const float*)d_in[2];
    const float* Wv = (const float*)d_in[3];
    float* out = (float*)d_out;

    unsigned short* ws   = (unsigned short*)d_ws;
    const size_t qkv_elems = (size_t)NB * NT * NH;   // 2M elements each
    unsigned short* qws  = ws;
    unsigned short* kws  = qws + qkv_elems;
    unsigned short* vtws = kws + qkv_elems;
    unsigned short* Wt   = vtws + qkv_elems;          // 192*1024 bf16
    float* opart  = (float*)(Wt + (size_t)192 * NC);  // 1024 tiles x 4096 f32
    float* mlpart = opart + (size_t)1024 * 4096;      // 1024 x 128 f32

    wprep_kernel<<<dim3(192), dim3(256), 0, stream>>>(Wk, Wq, Wv, Wt);
    proj_kernel<<<dim3(512), dim3(256), 0, stream>>>(x, Wt, qws, kws, vtws);
    flash_kernel<<<dim3(1024), dim3(256), 0, stream>>>(qws, kws, vtws, opart, mlpart);
    combine_kernel<<<dim3(512), dim3(256), 0, stream>>>(opart, mlpart, out);
}

// Round 12
// 86.445 us; speedup vs baseline: 2.8012x; 1.1156x over previous
//
#include <hip/hip_runtime.h>
#include <hip/hip_bf16.h>

// B=8, T=4096, C=1024, HS=64. Single attention head, causal, scale = C^-0.5.
// Pipeline: wprep (W -> Wt bf16 [192][1024]) ; proj (counted-vmcnt pipeline) ;
//           flash (hybrid split-KV: qt>=32 split in 2 halves -> partials,
//                  qt<32 unsplit -> direct final write; swapped-operand MFMA) ;
//           combine (merge partials for qt>=32 only).
// Q is pre-scaled by log2(e)/32 in proj, so QK^T is directly log2-domain.

typedef __attribute__((ext_vector_type(8))) short short8;
typedef __attribute__((ext_vector_type(4))) float f32x4;

#define NB 8
#define NT 4096
#define NC 1024
#define NH 64

__device__ __forceinline__ unsigned short f2bf(float f) {
    unsigned int u = __builtin_bit_cast(unsigned int, f);
    u += 0x7fffu + ((u >> 16) & 1u);   // RNE
    return (unsigned short)(u >> 16);
}

__device__ __forceinline__ unsigned cvt_pk_bf16(float lo, float hi) {
    unsigned r;
    asm("v_cvt_pk_bf16_f32 %0, %1, %2" : "=v"(r) : "v"(lo), "v"(hi));
    return r;
}

// async global->LDS, 16B per lane; LDS dest = wave-uniform base + lane*16
#define GLOAD16(gp, lp)                                                        \
    __builtin_amdgcn_global_load_lds(                                          \
        (const __attribute__((address_space(1))) void*)(gp),                   \
        (__attribute__((address_space(3))) void*)(lp), 16, 0, 0)

// ---------------- W prep: Wt[n][c] = W_{n/64}[c][n%64] as bf16 -----------------
__global__ __launch_bounds__(256) void wprep_kernel(
    const float* __restrict__ Wk, const float* __restrict__ Wq,
    const float* __restrict__ Wv, unsigned short* __restrict__ Wt)
{
    int n = blockIdx.x;            // 0..191
    int which = n >> 6, h = n & 63;
    const float* W = (which == 0) ? Wk : (which == 1) ? Wq : Wv;
    for (int c = threadIdx.x; c < NC; c += 256)
        Wt[(size_t)n * NC + c] = f2bf(W[(size_t)c * NH + h]);
}

// ---------------- Projection GEMM: [32768 x 1024] @ [1024 x 192] ---------------
// Counted-vmcnt pipeline: BK=32, 4 LDS buffers (20 KB each), depth-2 prefetch.
__global__ __launch_bounds__(256, 2) void proj_kernel(
    const float* __restrict__ x, const unsigned short* __restrict__ Wt,
    unsigned short* __restrict__ qws, unsigned short* __restrict__ kws,
    unsigned short* __restrict__ vtws)
{
    __shared__ char lds[4][20480];   // [buf]: A at 0 (8 KB), B at 8192 (12 KB)

    const int lane = threadIdx.x & 63;
    const int wave = threadIdx.x >> 6;
    const int l15 = lane & 15;
    const int kg = lane >> 4;                  // 0..3
    const int m0 = blockIdx.x * 64;

    const int agS = (lane & 7) ^ (lane >> 3);
    const float* aSrc[2];
#pragma unroll
    for (int j = 0; j < 2; ++j) {
        int i = wave * 2 + j;
        int r = 8 * i + (lane >> 3);
        aSrc[j] = x + (size_t)(m0 + r) * NC + agS * 4;
    }
    const int bgS = (lane & 3) ^ ((lane >> 2) & 3);
    const unsigned short* bSrc[3];
#pragma unroll
    for (int j = 0; j < 3; ++j) {
        int u = wave * 3 + j;
        int r = 16 * u + (lane >> 2);
        bSrc[j] = Wt + (size_t)r * NC + bgS * 8;
    }

    f32x4 acc[12];
#pragma unroll
    for (int i = 0; i < 12; ++i) acc[i] = f32x4{0.f, 0.f, 0.f, 0.f};

#define STAGE_CHUNK(c)                                                         \
    do {                                                                       \
        char* base_ = lds[(c) & 3];                                            \
        _Pragma("unroll")                                                      \
        for (int j = 0; j < 2; ++j)                                            \
            GLOAD16(aSrc[j] + (c) * 32, base_ + (wave * 2 + j) * 1024);        \
        _Pragma("unroll")                                                      \
        for (int j = 0; j < 3; ++j)                                            \
            GLOAD16(bSrc[j] + (c) * 32, base_ + 8192 + (wave * 3 + j) * 1024); \
    } while (0)

    STAGE_CHUNK(0);
    STAGE_CHUNK(1);

    for (int kc = 0; kc < 32; ++kc) {
        if (kc < 30) {
            STAGE_CHUNK(kc + 2);
            asm volatile("s_waitcnt vmcnt(10)" ::: "memory");
        } else if (kc == 30) {
            asm volatile("s_waitcnt vmcnt(5)" ::: "memory");
        } else {
            asm volatile("s_waitcnt vmcnt(0)" ::: "memory");
        }
        __builtin_amdgcn_sched_barrier(0);
        __builtin_amdgcn_s_barrier();

        const char* Ab = lds[kc & 3];
        const char* Bb = lds[kc & 3] + 8192;
        {
            const int r = wave * 16 + l15;
            const int g0 = kg * 2;
            f32x4 a0 = *(const f32x4*)(Ab + r * 128 + ((g0 ^ (r & 7)) * 16));
            f32x4 a1 = *(const f32x4*)(Ab + r * 128 + (((g0 + 1) ^ (r & 7)) * 16));
            short8 a;
            a[0] = (short)f2bf(a0[0]); a[1] = (short)f2bf(a0[1]);
            a[2] = (short)f2bf(a0[2]); a[3] = (short)f2bf(a0[3]);
            a[4] = (short)f2bf(a1[0]); a[5] = (short)f2bf(a1[1]);
            a[6] = (short)f2bf(a1[2]); a[7] = (short)f2bf(a1[3]);
#pragma unroll
            for (int nt = 0; nt < 12; ++nt) {
                int rb = nt * 16 + l15;
                short8 bfrag = *(const short8*)(
                    Bb + rb * 64 + ((kg ^ (rb & 3)) * 16));
                acc[nt] = __builtin_amdgcn_mfma_f32_16x16x32_bf16(a, bfrag, acc[nt], 0, 0, 0);
            }
        }
    }
#undef STAGE_CHUNK

    const float cs = 0.04508422f;   // log2(e) / 32  (folded into q)
    const int crow0 = m0 + wave * 16 + (kg << 2);
#pragma unroll
    for (int nt = 0; nt < 12; ++nt) {
        int n = nt * 16 + l15;
        int which = n >> 6;
        int h = n & 63;
#pragma unroll
        for (int r = 0; r < 4; ++r) {
            int gm = crow0 + r;
            float av = acc[nt][r];
            if (which == 1) av *= cs;
            unsigned short v = f2bf(av);
            if (which == 0) {
                kws[(size_t)gm * NH + h] = v;
            } else if (which == 1) {
                qws[(size_t)gm * NH + h] = v;
            } else {
                int bb = gm >> 12, tt = gm & 4095;
                vtws[((size_t)(bb * NH + h)) * NT + tt] = v;
            }
        }
    }
}

// ---------------- Flash attention (causal, swapped operands, hybrid split) -----
// 768 blocks: ids 0..511 = split blocks (qt 32..63, two KV halves, heavy first),
// ids 512..767 = unsplit blocks (qt 0..31, whole range, direct final write).
// id&7 = batch in all groups (keeps batch<->XCD L2 affinity).
// 4 waves x 16 q-rows; 64-key tiles; K/V dbuf via global_load_lds (R6 structure).
// Every partition is non-empty and every row has >=1 valid key (hsp <= qt).
__global__ __launch_bounds__(256) void flash_kernel(
    const unsigned short* __restrict__ qws, const unsigned short* __restrict__ kws,
    const unsigned short* __restrict__ vtws,
    float* __restrict__ opart, float* __restrict__ mlpart,
    float* __restrict__ out)
{
    __shared__ unsigned short Kbuf[2][64 * 64];
    __shared__ unsigned short Vbuf[2][64 * 64];
    __shared__ unsigned short Plds[4 * 16 * 64];   // per-wave 16x64 P strips

    const int id = blockIdx.x;
    int b, qt, k0, k1, pid;
    bool direct;
    if (id < 512) {
        direct = false;
        const int j = id >> 4;            // 0..31, heavy first
        qt = 63 - j;
        const int half = (id >> 3) & 1;
        b = id & 7;
        const int nkv = qt + 1;
        const int hsp = nkv - (nkv >> 1); // ceil(nkv/2), <= qt for qt>=32
        k0 = half ? hsp : 0;
        k1 = half ? nkv : hsp;
        pid = ((31 - j) << 4) | (half << 3) | b;   // (qt-32)<<4 | half<<3 | b
    } else {
        direct = true;
        const int r = id - 512;
        qt = 31 - (r >> 3);               // heavy first
        b = r & 7;
        k0 = 0; k1 = qt + 1;
        pid = 0;
    }

    const int lane = threadIdx.x & 63;
    const int wave = threadIdx.x >> 6;
    const int l15 = lane & 15;
    const int kg = lane >> 4;

    // ---- staging sources (pre-inverse-swizzled, loop-invariant per lane) ----
    const int sg = (lane & 7) ^ (lane >> 3);   // swizzled source granule
    const unsigned short* kSrc[2];
    const unsigned short* vSrc[2];
#pragma unroll
    for (int j = 0; j < 2; ++j) {
        int r = 16 * wave + 8 * j + (lane >> 3);   // tile-local row 0..63
        kSrc[j] = kws + ((size_t)(b * NT) + r) * NH + sg * 8;
        vSrc[j] = vtws + ((size_t)(b * NH + r)) * NT + sg * 8;
    }

    // Q fragments (pre-scaled by log2(e)/32): lane holds Q[q=l15][d=kg*8+j]
    short8 qf[2];
    {
        const unsigned short* qp =
            qws + ((size_t)(b * NT + qt * 64 + wave * 16 + l15)) * NH + kg * 8;
        qf[0] = *(const short8*)(qp);
        qf[1] = *(const short8*)(qp + 32);
    }

    f32x4 o[4];        // O^T: o[dt][r] = O[q=l15][d = dt*16 + kg*4 + r]
#pragma unroll
    for (int dt = 0; dt < 4; ++dt) o[dt] = f32x4{0.f, 0.f, 0.f, 0.f};
    float m_r = -INFINITY;   // row max (uniform across the row's 4 kg-lanes)
    float l_r = 0.f;         // per-lane PARTIAL sum (own 16 keys)

    char* pw = (char*)Plds + wave * 2048;
    const int pswz = (l15 & 7) << 4;

    // prologue: stage tile k0 into buf 0
#pragma unroll
    for (int j = 0; j < 2; ++j) {
        int i = 2 * wave + j;
        GLOAD16(kSrc[j] + (size_t)k0 * 64 * NH, (char*)Kbuf[0] + i * 1024);
        GLOAD16(vSrc[j] + (size_t)k0 * 64,      (char*)Vbuf[0] + i * 1024);
    }
    __syncthreads();

    int cur = 0;
    for (int kv = k0; kv < k1; ++kv) {
        // stage next tile into the other buffer (async, fire-and-forget)
        if (kv + 1 < k1) {
#pragma unroll
            for (int j = 0; j < 2; ++j) {
                int i = 2 * wave + j;
                GLOAD16(kSrc[j] + (size_t)(kv + 1) * 64 * NH,
                        (char*)Kbuf[cur ^ 1] + i * 1024);
                GLOAD16(vSrc[j] + (size_t)(kv + 1) * 64,
                        (char*)Vbuf[cur ^ 1] + i * 1024);
            }
        }

        const char* Kb = (const char*)Kbuf[cur];
        const char* Vb = (const char*)Vbuf[cur];

        // S^T = mfma(K, Q): st[jt][r] = S[q=l15][key = jt*16 + kg*4 + r]
        f32x4 st[4];
#pragma unroll
        for (int jt = 0; jt < 4; ++jt) st[jt] = f32x4{0.f, 0.f, 0.f, 0.f};
        __builtin_amdgcn_s_setprio(1);
#pragma unroll
        for (int ks = 0; ks < 2; ++ks) {
            const int cbb = ks * 64 + kg * 16;
#pragma unroll
            for (int jt = 0; jt < 4; ++jt) {
                int krow = jt * 16 + l15;
                short8 kf = *(const short8*)(Kb + krow * 128 +
                                             (cbb ^ ((krow & 7) << 4)));
                st[jt] = __builtin_amdgcn_mfma_f32_16x16x32_bf16(kf, qf[ks], st[jt], 0, 0, 0);
            }
        }
        __builtin_amdgcn_s_setprio(0);

        // causal mask: only the diagonal tile (uniform branch)
        if (kv == qt) {
#pragma unroll
            for (int jt = 0; jt < 4; ++jt)
#pragma unroll
                for (int r = 0; r < 4; ++r)
                    if (jt * 16 + (kg << 2) + r > wave * 16 + l15)
                        st[jt][r] = -1e30f;
        }

        // lane-local max over own 16 keys (no cross-lane)
        float lmax;
        {
            float t0 = fmaxf(fmaxf(st[0][0], st[0][1]), fmaxf(st[0][2], st[0][3]));
            float t1 = fmaxf(fmaxf(st[1][0], st[1][1]), fmaxf(st[1][2], st[1][3]));
            float t2 = fmaxf(fmaxf(st[2][0], st[2][1]), fmaxf(st[2][2], st[2][3]));
            float t3 = fmaxf(fmaxf(st[3][0], st[3][1]), fmaxf(st[3][2], st[3][3]));
            lmax = fmaxf(fmaxf(t0, t1), fmaxf(t2, t3));
        }

        // defer-max: rescale only when some row grew past m+8 (rare)
        if (!__all(lmax <= m_r + 8.0f)) {
            float pmax = lmax;
            pmax = fmaxf(pmax, __shfl_xor(pmax, 16));
            pmax = fmaxf(pmax, __shfl_xor(pmax, 32));
            float mn = fmaxf(m_r, pmax);
            float alpha = __builtin_amdgcn_exp2f(m_r - mn);
            m_r = mn;
            l_r *= alpha;
#pragma unroll
            for (int dt = 0; dt < 4; ++dt)
#pragma unroll
                for (int r = 0; r < 4; ++r)
                    o[dt][r] *= alpha;
        }

        // P = exp2(S - m), bounded by 2^8; accumulate per-lane partial l
#pragma unroll
        for (int jt = 0; jt < 4; ++jt)
#pragma unroll
            for (int r = 0; r < 4; ++r)
                st[jt][r] = __builtin_amdgcn_exp2f(st[jt][r] - m_r);
        {
            float t0 = (st[0][0] + st[0][1]) + (st[0][2] + st[0][3]);
            float t1 = (st[1][0] + st[1][1]) + (st[1][2] + st[1][3]);
            float t2 = (st[2][0] + st[2][1]) + (st[2][2] + st[2][3]);
            float t3 = (st[3][0] + st[3][1]) + (st[3][2] + st[3][3]);
            l_r += (t0 + t1) + (t2 + t3);
        }

        // pack P to bf16, per-wave LDS strip round-trip -> B-frag layout
#pragma unroll
        for (int jt = 0; jt < 4; ++jt) {
            unsigned w0 = cvt_pk_bf16(st[jt][0], st[jt][1]);
            unsigned w1 = cvt_pk_bf16(st[jt][2], st[jt][3]);
            uint2 t; t.x = w0; t.y = w1;
            *(uint2*)(pw + l15 * 128 + ((jt * 32 + kg * 8) ^ pswz)) = t;
        }
        short8 pf[2];
#pragma unroll
        for (int ks = 0; ks < 2; ++ks)
            pf[ks] = *(const short8*)(pw + l15 * 128 + ((ks * 64 + kg * 16) ^ pswz));

        // O^T += mfma(V^T, P^T)
        __builtin_amdgcn_s_setprio(1);
#pragma unroll
        for (int ks = 0; ks < 2; ++ks) {
            const int cbb = ks * 64 + kg * 16;
#pragma unroll
            for (int dt = 0; dt < 4; ++dt) {
                int vrow = dt * 16 + l15;
                short8 vf = *(const short8*)(Vb + vrow * 128 +
                                             (cbb ^ ((vrow & 7) << 4)));
                o[dt] = __builtin_amdgcn_mfma_f32_16x16x32_bf16(vf, pf[ks], o[dt], 0, 0, 0);
            }
        }
        __builtin_amdgcn_s_setprio(0);

        // single barrier: drains staging vmcnt + this iter's LDS reads
        __syncthreads();
        cur ^= 1;
    }

    // epilogue: reduce partial l across the row's 4 kg-lanes
    float lsum = l_r;
    lsum += __shfl_xor(lsum, 16);
    lsum += __shfl_xor(lsum, 32);
    const int q = wave * 16 + l15;

    if (direct) {
        // unsplit block: normalize and write final output
        float linv = __builtin_amdgcn_rcpf(lsum);
        float* grow = out + ((size_t)(b * NT) + qt * 64 + q) * NH + (kg << 2);
#pragma unroll
        for (int dt = 0; dt < 4; ++dt) {
            f32x4 v = o[dt];
            v[0] *= linv; v[1] *= linv; v[2] *= linv; v[3] *= linv;
            *(f32x4*)(grow + dt * 16) = v;
        }
    } else {
        // split block: store raw O^T + (m, l) partials
        float* op = opart + (size_t)pid * 4096;
        float* mlp = mlpart + (size_t)pid * 128;
        float* orow = op + q * 64 + (kg << 2);
#pragma unroll
        for (int dt = 0; dt < 4; ++dt)
            *(f32x4*)(orow + dt * 16) = o[dt];
        if (kg == 0) {
            mlp[q] = m_r;
            mlp[64 + q] = lsum;
        }
    }
}

// ---------------- Combine: merge the two KV halves (qt>=32 only) ---------------
// 256 blocks = (qti 0..31, b). O = (eA*OA + eB*OB) / (eA*lA + eB*lB).
__global__ __launch_bounds__(256) void combine_kernel(
    const float* __restrict__ opart, const float* __restrict__ mlpart,
    float* __restrict__ out)
{
    const int cid = blockIdx.x;          // = (qti<<3)|b
    const int qti = cid >> 3, b = cid & 7;
    const int qt = qti + 32;
    const int pidA = (qti << 4) | b;
    const int pidB = (qti << 4) | 8 | b;
    const float* mlA = mlpart + (size_t)pidA * 128;
    const float* mlB = mlpart + (size_t)pidB * 128;
    const f32x4* oA = (const f32x4*)(opart + (size_t)pidA * 4096);
    const f32x4* oB = (const f32x4*)(opart + (size_t)pidB * 4096);
    f32x4* og = (f32x4*)out;

#pragma unroll
    for (int i = 0; i < 4; ++i) {
        int g = threadIdx.x + i * 256;   // 0..1023 f32x4 groups
        int row = g >> 4;
        float mA = mlA[row], lA = mlA[64 + row];
        float mB = mlB[row], lB = mlB[64 + row];
        float ms = fmaxf(mA, mB);
        float eA = __builtin_amdgcn_exp2f(mA - ms);
        float eB = __builtin_amdgcn_exp2f(mB - ms);
        float dinv = __builtin_amdgcn_rcpf(eA * lA + eB * lB);
        f32x4 a = oA[g], c = oB[g];
        f32x4 r;
        r[0] = (eA * a[0] + eB * c[0]) * dinv;
        r[1] = (eA * a[1] + eB * c[1]) * dinv;
        r[2] = (eA * a[2] + eB * c[2]) * dinv;
        r[3] = (eA * a[3] + eB * c[3]) * dinv;
        og[((size_t)(b * NT) + qt * 64 + row) * 16 + (g & 15)] = r;
    }
}

extern "C" void kernel_launch(void* const* d_in, const int* in_sizes, int n_in,
                              void* d_out, int out_size, void* d_ws, size_t ws_size,
                              hipStream_t stream) {
    const float* x  = (const float*)d_in[0];
    const float* Wk = (const float*)d_in[1];
    const float* Wq = (const float*)d_in[2];
    const float* Wv = (const float*)d_in[3];
    float* out = (float*)d_out;

    unsigned short* ws   = (unsigned short*)d_ws;
    const size_t qkv_elems = (size_t)NB * NT * NH;   // 2M elements each
    unsigned short* qws  = ws;
    unsigned short* kws  = qws + qkv_elems;
    unsigned short* vtws = kws + qkv_elems;
    unsigned short* Wt   = vtws + qkv_elems;          // 192*1024 bf16
    float* opart  = (float*)(Wt + (size_t)192 * NC);  // 512 partials x 4096 f32
    float* mlpart = opart + (size_t)512 * 4096;       // 512 x 128 f32

    wprep_kernel<<<dim3(192), dim3(256), 0, stream>>>(Wk, Wq, Wv, Wt);
    proj_kernel<<<dim3(512), dim3(256), 0, stream>>>(x, Wt, qws, kws, vtws);
    flash_kernel<<<dim3(768), dim3(256), 0, stream>>>(qws, kws, vtws, opart, mlpart, out);
    combine_kernel<<<dim3(256), dim3(256), 0, stream>>>(opart, mlpart, out);
}

// Round 13
// 79.532 us; speedup vs baseline: 3.0447x; 1.0869x over previous
//
#include <hip/hip_runtime.h>
#include <hip/hip_bf16.h>

// B=8, T=4096, C=1024, HS=64. Single attention head, causal, scale = C^-0.5.
// Pipeline: wprep ; proj (counted-vmcnt) ; flash (32x32 MFMA, 32 q-rows/wave,
//           128-row q-tiles, 4-way KV split, in-register P via cvt_pk+shfl) ;
//           combine (merge 4 partials).
// Q is pre-scaled by log2(e)/32 in proj, so QK^T is directly log2-domain.

typedef __attribute__((ext_vector_type(8))) short short8;
typedef __attribute__((ext_vector_type(4))) float f32x4;
typedef __attribute__((ext_vector_type(16))) float f32x16;
typedef __attribute__((ext_vector_type(4))) unsigned int u32x4;

#define NB 8
#define NT 4096
#define NC 1024
#define NH 64

__device__ __forceinline__ unsigned short f2bf(float f) {
    unsigned int u = __builtin_bit_cast(unsigned int, f);
    u += 0x7fffu + ((u >> 16) & 1u);   // RNE
    return (unsigned short)(u >> 16);
}

__device__ __forceinline__ unsigned cvt_pk_bf16(float lo, float hi) {
    unsigned r;
    asm("v_cvt_pk_bf16_f32 %0, %1, %2" : "=v"(r) : "v"(lo), "v"(hi));
    return r;
}

// async global->LDS, 16B per lane; LDS dest = wave-uniform base + lane*16
#define GLOAD16(gp, lp)                                                        \
    __builtin_amdgcn_global_load_lds(                                          \
        (const __attribute__((address_space(1))) void*)(gp),                   \
        (__attribute__((address_space(3))) void*)(lp), 16, 0, 0)

// ---------------- W prep: Wt[n][c] = W_{n/64}[c][n%64] as bf16 -----------------
__global__ __launch_bounds__(256) void wprep_kernel(
    const float* __restrict__ Wk, const float* __restrict__ Wq,
    const float* __restrict__ Wv, unsigned short* __restrict__ Wt)
{
    int n = blockIdx.x;            // 0..191
    int which = n >> 6, h = n & 63;
    const float* W = (which == 0) ? Wk : (which == 1) ? Wq : Wv;
    for (int c = threadIdx.x; c < NC; c += 256)
        Wt[(size_t)n * NC + c] = f2bf(W[(size_t)c * NH + h]);
}

// ---------------- Projection GEMM: [32768 x 1024] @ [1024 x 192] ---------------
// Counted-vmcnt pipeline: BK=32, 4 LDS buffers (20 KB each), depth-2 prefetch.
__global__ __launch_bounds__(256, 2) void proj_kernel(
    const float* __restrict__ x, const unsigned short* __restrict__ Wt,
    unsigned short* __restrict__ qws, unsigned short* __restrict__ kws,
    unsigned short* __restrict__ vtws)
{
    __shared__ char lds[4][20480];   // [buf]: A at 0 (8 KB), B at 8192 (12 KB)

    const int lane = threadIdx.x & 63;
    const int wave = threadIdx.x >> 6;
    const int l15 = lane & 15;
    const int kg = lane >> 4;                  // 0..3
    const int m0 = blockIdx.x * 64;

    const int agS = (lane & 7) ^ (lane >> 3);
    const float* aSrc[2];
#pragma unroll
    for (int j = 0; j < 2; ++j) {
        int i = wave * 2 + j;
        int r = 8 * i + (lane >> 3);
        aSrc[j] = x + (size_t)(m0 + r) * NC + agS * 4;
    }
    const int bgS = (lane & 3) ^ ((lane >> 2) & 3);
    const unsigned short* bSrc[3];
#pragma unroll
    for (int j = 0; j < 3; ++j) {
        int u = wave * 3 + j;
        int r = 16 * u + (lane >> 2);
        bSrc[j] = Wt + (size_t)r * NC + bgS * 8;
    }

    f32x4 acc[12];
#pragma unroll
    for (int i = 0; i < 12; ++i) acc[i] = f32x4{0.f, 0.f, 0.f, 0.f};

#define STAGE_CHUNK(c)                                                         \
    do {                                                                       \
        char* base_ = lds[(c) & 3];                                            \
        _Pragma("unroll")                                                      \
        for (int j = 0; j < 2; ++j)                                            \
            GLOAD16(aSrc[j] + (c) * 32, base_ + (wave * 2 + j) * 1024);        \
        _Pragma("unroll")                                                      \
        for (int j = 0; j < 3; ++j)                                            \
            GLOAD16(bSrc[j] + (c) * 32, base_ + 8192 + (wave * 3 + j) * 1024); \
    } while (0)

    STAGE_CHUNK(0);
    STAGE_CHUNK(1);

    for (int kc = 0; kc < 32; ++kc) {
        if (kc < 30) {
            STAGE_CHUNK(kc + 2);
            asm volatile("s_waitcnt vmcnt(10)" ::: "memory");
        } else if (kc == 30) {
            asm volatile("s_waitcnt vmcnt(5)" ::: "memory");
        } else {
            asm volatile("s_waitcnt vmcnt(0)" ::: "memory");
        }
        __builtin_amdgcn_sched_barrier(0);
        __builtin_amdgcn_s_barrier();

        const char* Ab = lds[kc & 3];
        const char* Bb = lds[kc & 3] + 8192;
        {
            const int r = wave * 16 + l15;
            const int g0 = kg * 2;
            f32x4 a0 = *(const f32x4*)(Ab + r * 128 + ((g0 ^ (r & 7)) * 16));
            f32x4 a1 = *(const f32x4*)(Ab + r * 128 + (((g0 + 1) ^ (r & 7)) * 16));
            short8 a;
            a[0] = (short)f2bf(a0[0]); a[1] = (short)f2bf(a0[1]);
            a[2] = (short)f2bf(a0[2]); a[3] = (short)f2bf(a0[3]);
            a[4] = (short)f2bf(a1[0]); a[5] = (short)f2bf(a1[1]);
            a[6] = (short)f2bf(a1[2]); a[7] = (short)f2bf(a1[3]);
#pragma unroll
            for (int nt = 0; nt < 12; ++nt) {
                int rb = nt * 16 + l15;
                short8 bfrag = *(const short8*)(
                    Bb + rb * 64 + ((kg ^ (rb & 3)) * 16));
                acc[nt] = __builtin_amdgcn_mfma_f32_16x16x32_bf16(a, bfrag, acc[nt], 0, 0, 0);
            }
        }
    }
#undef STAGE_CHUNK

    const float cs = 0.04508422f;   // log2(e) / 32  (folded into q)
    const int crow0 = m0 + wave * 16 + (kg << 2);
#pragma unroll
    for (int nt = 0; nt < 12; ++nt) {
        int n = nt * 16 + l15;
        int which = n >> 6;
        int h = n & 63;
#pragma unroll
        for (int r = 0; r < 4; ++r) {
            int gm = crow0 + r;
            float av = acc[nt][r];
            if (which == 1) av *= cs;
            unsigned short v = f2bf(av);
            if (which == 0) {
                kws[(size_t)gm * NH + h] = v;
            } else if (which == 1) {
                qws[(size_t)gm * NH + h] = v;
            } else {
                int bb = gm >> 12, tt = gm & 4095;
                vtws[((size_t)(bb * NH + h)) * NT + tt] = v;
            }
        }
    }
}

// ---------------- Flash attention (32x32 MFMA, 128-row q-tiles, 4-way split) ----
// 1024 blocks: id = g*32 + p*8 + b  (g 0..31 -> qt via balance permutation,
// p = KV partition 0..3, b = batch = id&7 -> XCD/L2 affinity).
// Wave handles 32 q-rows. S^T = mfma32(K,Q): lane q = l&31, 16 keys/lane;
// softmax lane-local; P^T built in-register (cvt_pk + shfl_xor(32) + select);
// O^T += mfma32(V^T, P^T). K/V double-buffered via global_load_lds (32 KB LDS).
__global__ __launch_bounds__(256, 4) void flash_kernel(
    const unsigned short* __restrict__ qws, const unsigned short* __restrict__ kws,
    const unsigned short* __restrict__ vtws,
    float* __restrict__ opart, float* __restrict__ mlpart)
{
    __shared__ unsigned short Kbuf[2][64 * 64];    // 64 keys x 64 d, 128 B rows
    __shared__ unsigned short Vbuf[2][64 * 64];    // 64 d x 64 keys (V^T)

    const int id = blockIdx.x;
    const int g = id >> 5;
    const int p = (id >> 3) & 3;
    const int b = id & 7;
    const int a = g & 7, m = g >> 3;
    const int qt = (m == 0) ? 31 - a : (m == 1) ? 16 + a : (m == 2) ? 15 - a : a;
    const int n = 2 * qt + 2;          // KV tiles for this 128-row q-tile
    const int len = (n + 3) >> 2;
    const int k0 = p * len;
    const int k1 = (k0 + len < n) ? (k0 + len) : n;
    const int pid = id;

    float* mlp = mlpart + (size_t)pid * 256;
    float* op  = opart + (size_t)pid * 8192;

    const int lane = threadIdx.x & 63;
    const int wave = threadIdx.x >> 6;
    const int l31 = lane & 31;
    const int hi = lane >> 5;
    const int rsw = lane & 7;          // row swizzle bits for frag reads

    // staging sources (pre-inverse-swizzled; same layout as R6/R12)
    const int sg = (lane & 7) ^ (lane >> 3);
    const unsigned short* kSrc[2];
    const unsigned short* vSrc[2];
#pragma unroll
    for (int j = 0; j < 2; ++j) {
        int r = 16 * wave + 8 * j + (lane >> 3);   // tile-local row 0..63
        kSrc[j] = kws + ((size_t)(b * NT) + r) * NH + sg * 8;
        vSrc[j] = vtws + ((size_t)(b * NH + r)) * NT + sg * 8;
    }

    // Q fragments (B-operand): lane holds Q[d = s*16 + 8*hi + j][q = l31]
    const int qmin = qt * 128 + wave * 32;
    short8 qf[4];
    {
        const char* qp = (const char*)(qws + ((size_t)(b * NT) + qmin + l31) * NH);
#pragma unroll
        for (int s = 0; s < 4; ++s)
            qf[s] = *(const short8*)(qp + s * 32 + hi * 16);
    }

    f32x16 o0, o1;                     // O^T: d-tiles 0..31 / 32..63, q = l31
#pragma unroll
    for (int i = 0; i < 16; ++i) { o0[i] = 0.f; o1[i] = 0.f; }
    float m_r = -INFINITY;
    float l_r = 0.f;                   // per-lane partial (own 32 keys per tile)

    const int kst = (k0 < n) ? k0 : (n - 1);
#pragma unroll
    for (int j = 0; j < 2; ++j) {
        int i = 2 * wave + j;
        GLOAD16(kSrc[j] + (size_t)kst * 64 * NH, (char*)Kbuf[0] + i * 1024);
        GLOAD16(vSrc[j] + (size_t)kst * 64,      (char*)Vbuf[0] + i * 1024);
    }
    __syncthreads();

    int cur = 0;
    for (int kv = k0; kv < k1; ++kv) {
        if (kv + 1 < k1) {
#pragma unroll
            for (int j = 0; j < 2; ++j) {
                int i = 2 * wave + j;
                GLOAD16(kSrc[j] + (size_t)(kv + 1) * 64 * NH,
                        (char*)Kbuf[cur ^ 1] + i * 1024);
                GLOAD16(vSrc[j] + (size_t)(kv + 1) * 64,
                        (char*)Vbuf[cur ^ 1] + i * 1024);
            }
        }

        const char* Kb = (const char*)Kbuf[cur];
        const char* Vb = (const char*)Vbuf[cur];

        // S^T = mfma32(K, Q): st0 = keys kv*64+0..31, st1 = +32..63; q = l31
        f32x16 st0, st1;
#pragma unroll
        for (int i = 0; i < 16; ++i) { st0[i] = 0.f; st1[i] = 0.f; }
        __builtin_amdgcn_s_setprio(1);
#pragma unroll
        for (int s = 0; s < 4; ++s) {
            int gl = s * 2 + hi;                    // 16B granule in 128B row
            short8 ka = *(const short8*)(Kb + l31 * 128 + ((gl ^ rsw) << 4));
            short8 kb = *(const short8*)(Kb + (32 + l31) * 128 + ((gl ^ rsw) << 4));
            st0 = __builtin_amdgcn_mfma_f32_32x32x16_bf16(ka, qf[s], st0, 0, 0, 0);
            st1 = __builtin_amdgcn_mfma_f32_32x32x16_bf16(kb, qf[s], st1, 0, 0, 0);
        }
        __builtin_amdgcn_s_setprio(0);

        // causal mask (elementwise only when tile can cross the diagonal)
        const int kb0 = kv * 64;
        if (kb0 + 63 > qmin) {
            const int qg = qmin + l31;
#pragma unroll
            for (int r = 0; r < 16; ++r) {
                int key = kb0 + (r & 3) + 8 * (r >> 2) + 4 * hi;
                if (key > qg) st0[r] = -1e30f;
                if (key + 32 > qg) st1[r] = -1e30f;
            }
        }

        // lane-local max over own 32 values
        float lmax = st0[0];
#pragma unroll
        for (int r = 1; r < 16; ++r) lmax = fmaxf(lmax, st0[r]);
#pragma unroll
        for (int r = 0; r < 16; ++r) lmax = fmaxf(lmax, st1[r]);

        // defer-max: rescale only when some row grew past m+8 (rare)
        if (!__all(lmax <= m_r + 8.0f)) {
            float pmax = fmaxf(lmax, __shfl_xor(lmax, 32));
            float mn = fmaxf(m_r, pmax);
            float alpha = __builtin_amdgcn_exp2f(m_r - mn);
            m_r = mn;
            l_r *= alpha;
#pragma unroll
            for (int r = 0; r < 16; ++r) { o0[r] *= alpha; o1[r] *= alpha; }
        }

        // P = exp2(S - m); accumulate per-lane partial l
        float psum = 0.f;
#pragma unroll
        for (int r = 0; r < 16; ++r) {
            st0[r] = __builtin_amdgcn_exp2f(st0[r] - m_r);
            st1[r] = __builtin_amdgcn_exp2f(st1[r] - m_r);
            psum += st0[r] + st1[r];
        }
        l_r += psum;

        // per key-tile: build P^T B-frags in-register and run PV
        __builtin_amdgcn_s_setprio(1);
#pragma unroll
        for (int kt = 0; kt < 2; ++kt) {
            const f32x16& st = kt ? st1 : st0;
            unsigned pa0 = cvt_pk_bf16(st[0], st[1]),  pa1 = cvt_pk_bf16(st[2], st[3]);
            unsigned pb0 = cvt_pk_bf16(st[4], st[5]),  pb1 = cvt_pk_bf16(st[6], st[7]);
            unsigned pc0 = cvt_pk_bf16(st[8], st[9]),  pc1 = cvt_pk_bf16(st[10], st[11]);
            unsigned pd0 = cvt_pk_bf16(st[12], st[13]), pd1 = cvt_pk_bf16(st[14], st[15]);
            unsigned xa0 = __shfl_xor((int)pa0, 32), xa1 = __shfl_xor((int)pa1, 32);
            unsigned xb0 = __shfl_xor((int)pb0, 32), xb1 = __shfl_xor((int)pb1, 32);
            unsigned xc0 = __shfl_xor((int)pc0, 32), xc1 = __shfl_xor((int)pc1, 32);
            unsigned xd0 = __shfl_xor((int)pd0, 32), xd1 = __shfl_xor((int)pd1, 32);
            u32x4 wA, wB;
            wA[0] = hi ? xb0 : pa0;  wA[1] = hi ? xb1 : pa1;
            wA[2] = hi ? pb0 : xa0;  wA[3] = hi ? pb1 : xa1;
            wB[0] = hi ? xd0 : pc0;  wB[1] = hi ? xd1 : pc1;
            wB[2] = hi ? pd0 : xc0;  wB[3] = hi ? pd1 : xc1;
            short8 pfA = __builtin_bit_cast(short8, wA);
            short8 pfB = __builtin_bit_cast(short8, wB);
#pragma unroll
            for (int w = 0; w < 2; ++w) {           // key window within tile
                short8 pf = w ? pfB : pfA;
                int gv = (kt * 2 + w) * 2 + hi;     // granule over 64-key row
                short8 va = *(const short8*)(Vb + l31 * 128 + ((gv ^ rsw) << 4));
                short8 vb = *(const short8*)(Vb + (32 + l31) * 128 + ((gv ^ rsw) << 4));
                o0 = __builtin_amdgcn_mfma_f32_32x32x16_bf16(va, pf, o0, 0, 0, 0);
                o1 = __builtin_amdgcn_mfma_f32_32x32x16_bf16(vb, pf, o1, 0, 0, 0);
            }
        }
        __builtin_amdgcn_s_setprio(0);

        __syncthreads();   // staging landed + this iter's LDS reads done
        cur ^= 1;
    }

    // epilogue: total l (partner holds other 32 keys), store partial O^T + (m,l)
    float lt = l_r + __shfl_xor(l_r, 32);
    const int row = wave * 32 + l31;
    float* orow = op + row * 64;
#pragma unroll
    for (int blk = 0; blk < 4; ++blk) {
        f32x4 v0, v1;
#pragma unroll
        for (int r = 0; r < 4; ++r) { v0[r] = o0[blk * 4 + r]; v1[r] = o1[blk * 4 + r]; }
        *(f32x4*)(orow + 8 * blk + 4 * hi) = v0;
        *(f32x4*)(orow + 32 + 8 * blk + 4 * hi) = v1;
    }
    if (hi == 0) {
        mlp[row] = m_r;
        mlp[128 + row] = lt;
    }
}

// ---------------- Combine: merge 4 KV partitions, normalize --------------------
// 256 blocks = (qt 0..31)<<3 | b. O = sum_p e_p*O_p / sum_p e_p*l_p.
__global__ __launch_bounds__(256) void combine_kernel(
    const float* __restrict__ opart, const float* __restrict__ mlpart,
    float* __restrict__ out)
{
    const int cid = blockIdx.x;
    const int qt = cid >> 3, b = cid & 7;
    int g;
    if (qt >= 24) g = 31 - qt;
    else if (qt >= 16) g = 8 + (qt - 16);
    else if (qt >= 8) g = 16 + (15 - qt);
    else g = 24 + qt;
    const int pidb = g * 32 + b;      // + p*8

    const float* ml[4];
    const f32x4* ov[4];
#pragma unroll
    for (int p = 0; p < 4; ++p) {
        ml[p] = mlpart + (size_t)(pidb + p * 8) * 256;
        ov[p] = (const f32x4*)(opart + (size_t)(pidb + p * 8) * 8192);
    }
    f32x4* og = (f32x4*)out;

#pragma unroll
    for (int i = 0; i < 8; ++i) {
        int gidx = threadIdx.x + i * 256;   // 0..2047 f32x4 groups
        int row = gidx >> 4;
        float m0 = ml[0][row], m1 = ml[1][row], m2 = ml[2][row], m3 = ml[3][row];
        float ms = fmaxf(fmaxf(m0, m1), fmaxf(m2, m3));
        float e0 = __builtin_amdgcn_exp2f(m0 - ms);
        float e1 = __builtin_amdgcn_exp2f(m1 - ms);
        float e2 = __builtin_amdgcn_exp2f(m2 - ms);
        float e3 = __builtin_amdgcn_exp2f(m3 - ms);
        float den = e0 * ml[0][128 + row] + e1 * ml[1][128 + row] +
                    e2 * ml[2][128 + row] + e3 * ml[3][128 + row];
        float dinv = __builtin_amdgcn_rcpf(den);
        f32x4 a0 = ov[0][gidx], a1 = ov[1][gidx], a2 = ov[2][gidx], a3 = ov[3][gidx];
        f32x4 r;
#pragma unroll
        for (int c = 0; c < 4; ++c)
            r[c] = (e0 * a0[c] + e1 * a1[c] + e2 * a2[c] + e3 * a3[c]) * dinv;
        og[((size_t)(b * NT) + qt * 128 + row) * 16 + (gidx & 15)] = r;
    }
}

extern "C" void kernel_launch(void* const* d_in, const int* in_sizes, int n_in,
                              void* d_out, int out_size, void* d_ws, size_t ws_size,
                              hipStream_t stream) {
    const float* x  = (const float*)d_in[0];
    const float* Wk = (const float*)d_in[1];
    const float* Wq = (const float*)d_in[2];
    const float* Wv = (const float*)d_in[3];
    float* out = (float*)d_out;

    unsigned short* ws   = (unsigned short*)d_ws;
    const size_t qkv_elems = (size_t)NB * NT * NH;   // 2M elements each
    unsigned short* qws  = ws;
    unsigned short* kws  = qws + qkv_elems;
    unsigned short* vtws = kws + qkv_elems;
    unsigned short* Wt   = vtws + qkv_elems;          // 192*1024 bf16
    float* opart  = (float*)(Wt + (size_t)192 * NC);  // 1024 partials x 8192 f32
    float* mlpart = opart + (size_t)1024 * 8192;      // 1024 x 256 f32

    wprep_kernel<<<dim3(192), dim3(256), 0, stream>>>(Wk, Wq, Wv, Wt);
    proj_kernel<<<dim3(512), dim3(256), 0, stream>>>(x, Wt, qws, kws, vtws);
    flash_kernel<<<dim3(1024), dim3(256), 0, stream>>>(qws, kws, vtws, opart, mlpart);
    combine_kernel<<<dim3(256), dim3(256), 0, stream>>>(opart, mlpart, out);
}